// Round 17
// baseline (551.158 us; speedup 1.0000x reference)
//
#include <hip/hip_runtime.h>
#include <hip/hip_bf16.h>
#include <math.h>

#define N_NODES    100000
#define N_EDGES    1600000
#define FDIM       128
#define NUM_GRAPHS 512
#define EPS        1e-5f
#define PADN       100096           // 782 * 128

#define B_WPK   192                 // 3 * 64

#define NBUCK   196                 // ceil(100000/512)
#define CAPA    9216                // per-bucket capacity (mean 8163, sigma ~90)
#define EB_CHUNK 2048               // edges per binning block (proven optimum)
#define BIN_BLOCKS ((N_EDGES + EB_CHUNK - 1) / EB_CHUNK)   // 782
#define SEGSH   14                  // src segment = src >> 14
#define SEGN    8

typedef __attribute__((ext_vector_type(8))) __bf16 bf16x8;
typedef __attribute__((ext_vector_type(4))) float  f32x4;

__device__ __forceinline__ unsigned short f2bf(float f) {
    unsigned u = __builtin_bit_cast(unsigned, f);
    u += 0x7FFF + ((u >> 16) & 1);           // round-to-nearest-even
    return (unsigned short)(u >> 16);
}

// decode 4 packed fp8(e4m3) -> 4 floats
__device__ __forceinline__ void dec4(unsigned dw, float* o) {
    auto lo = __builtin_amdgcn_cvt_pk_f32_fp8(dw, false);
    auto hi = __builtin_amdgcn_cvt_pk_f32_fp8(dw, true);
    o[0] = lo[0]; o[1] = lo[1]; o[2] = hi[0]; o[3] = hi[1];
}

__device__ __forceinline__ void acc16(uint4 v, float* a) {
    float d[16];
    dec4(v.x, &d[0]); dec4(v.y, &d[4]); dec4(v.z, &d[8]); dec4(v.w, &d[12]);
#pragma unroll
    for (int f = 0; f < 16; f++) a[f] += d[f];
}

// agg core (float out): gather-sum dinv-pre-scaled fp8 rows for node i,
// di-scale + bias + LN + ReLU -> r[16] floats (features sl*16..sl*16+15)
// 4-deep gather ILP with cross-batch index prefetch (proven optimum, 48-52 VGPR)
__device__ __forceinline__ void agg_core_f(const unsigned char* __restrict__ h8,
                                           const int* __restrict__ offs,
                                           const int* __restrict__ csr_src,
                                           float di, int i, int sl,
                                           const float* __restrict__ bias,
                                           const float* __restrict__ gamma,
                                           const float* __restrict__ beta,
                                           float* r) {
    size_t lofs16 = (size_t)sl * 16;
    float a[16];
    {
        uint4 v = *(const uint4*)(h8 + (size_t)i * 128 + lofs16);
        float d[16];
        dec4(v.x, &d[0]); dec4(v.y, &d[4]); dec4(v.z, &d[8]); dec4(v.w, &d[12]);
#pragma unroll
        for (int f = 0; f < 16; f++) a[f] = d[f];
    }

    int eBeg = offs[i], eEnd = offs[i + 1];
    int e = eBeg;
    int s0, s1, s2, s3;
    if (e + 4 <= eEnd) {
        s0 = csr_src[e + 0]; s1 = csr_src[e + 1];
        s2 = csr_src[e + 2]; s3 = csr_src[e + 3];
    }
    for (; e + 8 <= eEnd; e += 4) {
        uint4 v0 = *(const uint4*)(h8 + (size_t)s0 * 128 + lofs16);
        uint4 v1 = *(const uint4*)(h8 + (size_t)s1 * 128 + lofs16);
        uint4 v2 = *(const uint4*)(h8 + (size_t)s2 * 128 + lofs16);
        uint4 v3 = *(const uint4*)(h8 + (size_t)s3 * 128 + lofs16);
        s0 = csr_src[e + 4]; s1 = csr_src[e + 5];
        s2 = csr_src[e + 6]; s3 = csr_src[e + 7];
        acc16(v0, a); acc16(v1, a); acc16(v2, a); acc16(v3, a);
    }
    if (e + 4 <= eEnd) {
        uint4 v0 = *(const uint4*)(h8 + (size_t)s0 * 128 + lofs16);
        uint4 v1 = *(const uint4*)(h8 + (size_t)s1 * 128 + lofs16);
        uint4 v2 = *(const uint4*)(h8 + (size_t)s2 * 128 + lofs16);
        uint4 v3 = *(const uint4*)(h8 + (size_t)s3 * 128 + lofs16);
        acc16(v0, a); acc16(v1, a); acc16(v2, a); acc16(v3, a);
        e += 4;
    }
    for (; e < eEnd; ++e) {
        int s = csr_src[e];
        uint4 v = *(const uint4*)(h8 + (size_t)s * 128 + lofs16);
        acc16(v, a);
    }

    float4 b0 = *(const float4*)(bias + sl * 16);
    float4 b1 = *(const float4*)(bias + sl * 16 + 4);
    float4 b2 = *(const float4*)(bias + sl * 16 + 8);
    float4 b3 = *(const float4*)(bias + sl * 16 + 12);
    a[0]  = fmaf(a[0],  di, b0.x); a[1]  = fmaf(a[1],  di, b0.y);
    a[2]  = fmaf(a[2],  di, b0.z); a[3]  = fmaf(a[3],  di, b0.w);
    a[4]  = fmaf(a[4],  di, b1.x); a[5]  = fmaf(a[5],  di, b1.y);
    a[6]  = fmaf(a[6],  di, b1.z); a[7]  = fmaf(a[7],  di, b1.w);
    a[8]  = fmaf(a[8],  di, b2.x); a[9]  = fmaf(a[9],  di, b2.y);
    a[10] = fmaf(a[10], di, b2.z); a[11] = fmaf(a[11], di, b2.w);
    a[12] = fmaf(a[12], di, b3.x); a[13] = fmaf(a[13], di, b3.y);
    a[14] = fmaf(a[14], di, b3.z); a[15] = fmaf(a[15], di, b3.w);

    float s1v = 0.f, s2v = 0.f;
#pragma unroll
    for (int f = 0; f < 16; f++) { s1v += a[f]; s2v += a[f] * a[f]; }
#pragma unroll
    for (int off = 1; off < 8; off <<= 1) {
        s1v += __shfl_xor(s1v, off);
        s2v += __shfl_xor(s2v, off);
    }
    float mu   = s1v * (1.0f / 128.0f);
    float var  = s2v * (1.0f / 128.0f) - mu * mu;
    float rstd = rsqrtf(var + EPS);

    float4 g0 = *(const float4*)(gamma + sl * 16);
    float4 g1 = *(const float4*)(gamma + sl * 16 + 4);
    float4 g2 = *(const float4*)(gamma + sl * 16 + 8);
    float4 g3 = *(const float4*)(gamma + sl * 16 + 12);
    float4 e0v = *(const float4*)(beta + sl * 16);
    float4 e1v = *(const float4*)(beta + sl * 16 + 4);
    float4 e2v = *(const float4*)(beta + sl * 16 + 8);
    float4 e3v = *(const float4*)(beta + sl * 16 + 12);
    float g[16]  = {g0.x,g0.y,g0.z,g0.w, g1.x,g1.y,g1.z,g1.w,
                    g2.x,g2.y,g2.z,g2.w, g3.x,g3.y,g3.z,g3.w};
    float be[16] = {e0v.x,e0v.y,e0v.z,e0v.w, e1v.x,e1v.y,e1v.z,e1v.w,
                    e2v.x,e2v.y,e2v.z,e2v.w, e3v.x,e3v.y,e3v.z,e3v.w};

#pragma unroll
    for (int f = 0; f < 16; f++)
        r[f] = fmaxf((a[f] - mu) * rstd * g[f] + be[f], 0.f);
}

// ---------------- k_pre: edge binning ∥ W pack ------------------------------

__global__ __launch_bounds__(256) void k_pre(const int* __restrict__ src,
                                             const int* __restrict__ dst,
                                             int* __restrict__ bcur,
                                             unsigned* __restrict__ binned,
                                             const float* __restrict__ W1,
                                             const float* __restrict__ W2,
                                             const float* __restrict__ W3,
                                             unsigned short* __restrict__ wp) {
    __shared__ int hist[NBUCK];
    __shared__ int lbase[NBUCK];
    __shared__ int loff[NBUCK];
    __shared__ unsigned lpack[EB_CHUNK];
    __shared__ unsigned short lbuck[EB_CHUNK];
    int b = blockIdx.x;
    int t = threadIdx.x;
    if (b < BIN_BLOCKS) {
        int e0 = b * EB_CHUNK;
        int nE = min(EB_CHUNK, N_EDGES - e0);

        for (int j = t; j < NBUCK; j += 256) { hist[j] = 0; loff[j] = 0; }
        __syncthreads();

        for (int k = t; k < nE; k += 256) {
            int e  = e0 + k;
            int d  = dst[e];
            int bk = d >> 9;
            lpack[k] = (unsigned)src[e] | ((unsigned)(d & 511) << 17);
            lbuck[k] = (unsigned short)bk;
            atomicAdd(&hist[bk], 1);
        }
        __syncthreads();
        for (int j = t; j < NBUCK; j += 256)
            lbase[j] = atomicAdd(&bcur[j], hist[j]);
        __syncthreads();

        for (int k = t; k < nE; k += 256) {
            int bk = lbuck[k];
            int p  = lbase[bk] + atomicAdd(&loff[bk], 1);
            binned[(size_t)bk * CAPA + p] = lpack[k];
        }
    } else {
        int wb  = b - BIN_BLOCKS;
        int mat = wb >> 6;
        const float* W = (mat == 0) ? W1 : (mat == 1) ? W2 : W3;
        unsigned short* o = wp + (size_t)mat * 16384;
        int idx = (wb & 63) * 256 + t;
        int j  = idx & 7;
        int l  = (idx >> 3) & 63;
        int ct = (idx >> 9) & 7;
        int ks = idx >> 12;
        int k  = ks * 32 + (l >> 4) * 8 + j;
        int c  = ct * 16 + (l & 15);
        o[idx] = f2bf(W[k * 128 + c]);
    }
}

// ---------------- k_binB: 2-level counting sort (direct scatter) ------------

__global__ __launch_bounds__(256) void k_binB(const unsigned* __restrict__ binned,
                                              const int* __restrict__ bcur,
                                              int* __restrict__ offs,
                                              float* __restrict__ dinv,
                                              int* __restrict__ csr_src) {
    __shared__ int smem[512 * SEGN + 256];   // 17 KB
    int* cnt2 = smem;
    int* part = smem + 4096;
    int b = blockIdx.x;
    int t = threadIdx.x;
    int nb0 = b * 512;
    int cnt = bcur[b];

    int pv = (t < b) ? bcur[t] : 0;
#pragma unroll
    for (int off = 32; off; off >>= 1) pv += __shfl_down(pv, off);
    if ((t & 63) == 0) part[t >> 6] = pv;
    __syncthreads();
    int seg0 = part[0] + part[1] + part[2] + part[3];
    __syncthreads();

    for (int j = t; j < 512 * SEGN; j += 256) cnt2[j] = 0;
    __syncthreads();

    for (int k = t; k < cnt; k += 256) {
        unsigned v = binned[(size_t)b * CAPA + k];
        atomicAdd(&cnt2[(v >> 17) * SEGN + ((v & 0x1FFFF) >> SEGSH)], 1);
    }
    __syncthreads();

    int base16 = t * 16;
    int lsum[16];
    int run = 0;
#pragma unroll
    for (int q = 0; q < 16; q++) { lsum[q] = run; run += cnt2[base16 + q]; }
    int deg0 = lsum[8];
    int deg1 = run - lsum[8];
    part[t] = run;
    __syncthreads();
    for (int off = 1; off < 256; off <<= 1) {
        int y = 0;
        if (t >= off) y = part[t - off];
        __syncthreads();
        if (t >= off) part[t] += y;
        __syncthreads();
    }
    int excl = part[t] - run;
#pragma unroll
    for (int q = 0; q < 16; q++) cnt2[base16 + q] = excl + lsum[q];

    {
        int n0 = nb0 + 2 * t;
        if (n0 < N_NODES) {
            offs[n0] = seg0 + excl;
            dinv[n0] = rsqrtf(1.0f + (float)deg0);
        }
        if (n0 + 1 < N_NODES) {
            offs[n0 + 1] = seg0 + excl + lsum[8];
            dinv[n0 + 1] = rsqrtf(1.0f + (float)deg1);
        }
    }
    if (b == NBUCK - 1 && t == 0) offs[N_NODES] = N_EDGES;
    __syncthreads();

    for (int k = t; k < cnt; k += 256) {
        unsigned v = binned[(size_t)b * CAPA + k];
        int p = atomicAdd(&cnt2[(v >> 17) * SEGN + ((v & 0x1FFFF) >> SEGSH)], 1);
        csr_src[seg0 + p] = (int)(v & 0x1FFFF);
    }
}

// ---------------- k_gemm1: C8 = fp8( dinv * (f32 x @ W1) ) ------------------

__global__ __launch_bounds__(256) void k_gemm1(const float* __restrict__ X,
                                               const unsigned short* __restrict__ Wp,
                                               const float* __restrict__ dinv,
                                               unsigned char* __restrict__ C8) {
    int t    = threadIdx.x;
    int lane = t & 63;
    int w    = t >> 6;
    int wc   = w & 1;
    int wr   = w >> 1;
    int rb   = blockIdx.x * 128 + wr * 64 + (lane & 15);
    int koff = (lane >> 4) * 8;

    f32x4 acc[4][4];
#pragma unroll
    for (int c = 0; c < 4; c++)
#pragma unroll
        for (int r = 0; r < 4; r++) acc[c][r] = (f32x4){0.f, 0.f, 0.f, 0.f};

    const bf16x8* Wv = (const bf16x8*)Wp;
#pragma unroll
    for (int ks = 0; ks < 4; ++ks) {
        bf16x8 fw[4], fa[4];
#pragma unroll
        for (int c = 0; c < 4; ++c)
            fw[c] = Wv[(ks * 8 + wc * 4 + c) * 64 + lane];
#pragma unroll
        for (int r = 0; r < 4; ++r) {
            int row = rb + r * 16;
            ushort4 lo = {0,0,0,0}, hi = {0,0,0,0};
            if (row < N_NODES) {
                const float* xp = X + (size_t)row * 128 + ks * 32 + koff;
                float4 xv0 = *(const float4*)xp;
                float4 xv1 = *(const float4*)(xp + 4);
                lo.x = f2bf(xv0.x); lo.y = f2bf(xv0.y);
                lo.z = f2bf(xv0.z); lo.w = f2bf(xv0.w);
                hi.x = f2bf(xv1.x); hi.y = f2bf(xv1.y);
                hi.z = f2bf(xv1.z); hi.w = f2bf(xv1.w);
            }
            uint4 packed = make_uint4(
                (unsigned)lo.x | ((unsigned)lo.y << 16),
                (unsigned)lo.z | ((unsigned)lo.w << 16),
                (unsigned)hi.x | ((unsigned)hi.y << 16),
                (unsigned)hi.z | ((unsigned)hi.w << 16));
            fa[r] = __builtin_bit_cast(bf16x8, packed);
        }
#pragma unroll
        for (int c = 0; c < 4; ++c)
#pragma unroll
            for (int r = 0; r < 4; ++r)
                acc[c][r] = __builtin_amdgcn_mfma_f32_16x16x32_bf16(fw[c], fa[r], acc[c][r], 0, 0, 0);
    }

#pragma unroll
    for (int r = 0; r < 4; ++r) {
        int row = blockIdx.x * 128 + wr * 64 + r * 16 + (lane & 15);
        if (row < N_NODES) {
            float dv = dinv[row];
#pragma unroll
            for (int c = 0; c < 4; ++c) {
                int col = (wc * 4 + c) * 16 + (lane >> 4) * 4;
                unsigned u = __builtin_amdgcn_cvt_pk_fp8_f32(acc[c][r][0] * dv, acc[c][r][1] * dv, 0, false);
                u = (unsigned)__builtin_amdgcn_cvt_pk_fp8_f32(acc[c][r][2] * dv, acc[c][r][3] * dv, (int)u, true);
                *(unsigned*)(C8 + (size_t)row * 128 + col) = u;
            }
        }
    }
}

// ---------------- k_fused: agg(l)+LN+ReLU -> 32-row LDS tile -> @W(l+1) -----
// launch_bounds(256, 8): request 8 waves/SIMD — VGPR 52 fits the 64 budget.

__global__ __launch_bounds__(256, 8) void k_fused(const unsigned char* __restrict__ h8_in,
                                                  const unsigned short* __restrict__ Wp,
                                                  const float* __restrict__ dinv,
                                                  unsigned char* __restrict__ h8_out,
                                                  const int* __restrict__ offs,
                                                  const int* __restrict__ csr_src,
                                                  const float* __restrict__ bias,
                                                  const float* __restrict__ gamma,
                                                  const float* __restrict__ beta) {
    __shared__ unsigned tile_u[32 * 64];      // 8 KB
    int t    = threadIdx.x;
    int lane = t & 63;
    int w    = t >> 6;
    int grp  = lane >> 3;
    int sl   = lane & 7;
    int nt   = w * 8 + grp;                   // 0..31
    int i    = blockIdx.x * 32 + nt;          // 3125*32 == 100000

    {
        float r[16];
        agg_core_f(h8_in, offs, csr_src, dinv[i], i, sl, bias, gamma, beta, r);
        unsigned ow[8];
#pragma unroll
        for (int f = 0; f < 8; f++)
            ow[f] = (unsigned)f2bf(r[2 * f]) | ((unsigned)f2bf(r[2 * f + 1]) << 16);
        int rowbase = nt * 64;
        int colu    = sl * 8;
        int swz0 = (colu    ) ^ ((nt & 15) << 2);
        int swz1 = (colu + 4) ^ ((nt & 15) << 2);
        *(uint4*)&tile_u[rowbase + swz0] = make_uint4(ow[0], ow[1], ow[2], ow[3]);
        *(uint4*)&tile_u[rowbase + swz1] = make_uint4(ow[4], ow[5], ow[6], ow[7]);
    }
    __syncthreads();

    f32x4 acc[2][2];
#pragma unroll
    for (int c = 0; c < 2; c++)
#pragma unroll
        for (int r = 0; r < 2; r++) acc[c][r] = (f32x4){0.f, 0.f, 0.f, 0.f};

    const bf16x8* Wv = (const bf16x8*)Wp;
#pragma unroll
    for (int ks = 0; ks < 4; ++ks) {
        bf16x8 fw[2], fa[2];
#pragma unroll
        for (int c = 0; c < 2; ++c)
            fw[c] = Wv[(ks * 8 + w * 2 + c) * 64 + lane];
#pragma unroll
        for (int r = 0; r < 2; ++r) {
            int lr   = r * 16 + (lane & 15);
            int colu = ks * 16 + (lane >> 4) * 4;
            int swz  = colu ^ ((lr & 15) << 2);
            uint4 v = *(const uint4*)&tile_u[lr * 64 + swz];
            fa[r] = __builtin_bit_cast(bf16x8, v);
        }
#pragma unroll
        for (int c = 0; c < 2; ++c)
#pragma unroll
            for (int r = 0; r < 2; ++r)
                acc[c][r] = __builtin_amdgcn_mfma_f32_16x16x32_bf16(fw[c], fa[r], acc[c][r], 0, 0, 0);
    }

#pragma unroll
    for (int r = 0; r < 2; ++r) {
        int row = blockIdx.x * 32 + r * 16 + (lane & 15);
        float dv = dinv[row];
#pragma unroll
        for (int c = 0; c < 2; ++c) {
            int col = (w * 2 + c) * 16 + (lane >> 4) * 4;
            unsigned u = __builtin_amdgcn_cvt_pk_fp8_f32(acc[c][r][0] * dv, acc[c][r][1] * dv, 0, false);
            u = (unsigned)__builtin_amdgcn_cvt_pk_fp8_f32(acc[c][r][2] * dv, acc[c][r][3] * dv, (int)u, true);
            *(unsigned*)(h8_out + (size_t)row * 128 + col) = u;
        }
    }
}

// ---------------- k_aggpool: agg3+LN3+ReLU + per-graph pooled sums ----------

__global__ __launch_bounds__(256, 8) void k_aggpool(const unsigned char* __restrict__ h8,
                                                    const int* __restrict__ offs,
                                                    const int* __restrict__ csr_src,
                                                    const float* __restrict__ dinv,
                                                    const int* __restrict__ batch,
                                                    const float* __restrict__ bias,
                                                    const float* __restrict__ gamma,
                                                    const float* __restrict__ beta,
                                                    float* __restrict__ pooled) {
    __shared__ float wsum[4][128];
    __shared__ int grange[2];
    int t    = threadIdx.x;
    int lane = t & 63;
    int w    = t >> 6;
    int grp  = lane >> 3;
    int sl   = lane & 7;
    int i    = blockIdx.x * 32 + w * 8 + grp;   // 3125*32 == 100000

    float r[16];
    agg_core_f(h8, offs, csr_src, dinv[i], i, sl, bias, gamma, beta, r);

    int bg = batch[i];
    if (t == 0) {
        grange[0] = batch[blockIdx.x * 32];
        grange[1] = batch[blockIdx.x * 32 + 31];
    }
    __syncthreads();
    int g0 = grange[0], g1 = grange[1];

    for (int g = g0; g <= g1; ++g) {
        float v[16];
        bool in = (bg == g);
#pragma unroll
        for (int f = 0; f < 16; f++) v[f] = in ? r[f] : 0.f;
#pragma unroll
        for (int f = 0; f < 16; f++) {
            v[f] += __shfl_xor(v[f], 8);
            v[f] += __shfl_xor(v[f], 16);
            v[f] += __shfl_xor(v[f], 32);
        }
        if (grp == 0) {
#pragma unroll
            for (int f = 0; f < 16; f++) wsum[w][sl * 16 + f] = v[f];
        }
        __syncthreads();
        if (t < 128) {
            float s = wsum[0][t] + wsum[1][t] + wsum[2][t] + wsum[3][t];
            if (s != 0.f) atomicAdd(&pooled[(size_t)g * 128 + t], s);
        }
        __syncthreads();
    }
}

// ---------------- k_final: out[g] = (pooled[g]/cnt[g]) . Wl + bl ------------

__global__ __launch_bounds__(64) void k_final(const float* __restrict__ pooled,
                                              const int* __restrict__ batch,
                                              const float* __restrict__ Wl,
                                              const float* __restrict__ bl,
                                              float* __restrict__ out) {
    int g = blockIdx.x;
    int lane = threadIdx.x;

    int lo = 0, hi = N_NODES;
    while (lo < hi) { int mid = (lo + hi) >> 1; if (batch[mid] < g) lo = mid + 1; else hi = mid; }
    int s = lo;
    lo = s; hi = N_NODES;
    while (lo < hi) { int mid = (lo + hi) >> 1; if (batch[mid] < g + 1) lo = mid + 1; else hi = mid; }
    int e = lo;

    float inv = 1.0f / fmaxf((float)(e - s), 1.0f);
    float2 p2 = ((const float2*)(pooled + (size_t)g * 128))[lane];
    float p = p2.x * inv * Wl[lane * 2] + p2.y * inv * Wl[lane * 2 + 1];
#pragma unroll
    for (int off = 32; off; off >>= 1) p += __shfl_xor(p, off);
    if (lane == 0) out[g] = p + bl[0];
}

// ---------------- launch ----------------

extern "C" void kernel_launch(void* const* d_in, const int* in_sizes, int n_in,
                              void* d_out, int out_size, void* d_ws, size_t ws_size,
                              hipStream_t stream) {
    const float* x     = (const float*)d_in[0];
    const int*   ei    = (const int*)d_in[1];
    const int*   batch = (const int*)d_in[2];
    const float* W1 = (const float*)d_in[3];
    const float* b1 = (const float*)d_in[4];
    const float* g1 = (const float*)d_in[5];
    const float* be1 = (const float*)d_in[6];
    const float* W2 = (const float*)d_in[7];
    const float* b2 = (const float*)d_in[8];
    const float* g2 = (const float*)d_in[9];
    const float* be2 = (const float*)d_in[10];
    const float* W3 = (const float*)d_in[11];
    const float* b3 = (const float*)d_in[12];
    const float* g3 = (const float*)d_in[13];
    const float* be3 = (const float*)d_in[14];
    const float* Wl = (const float*)d_in[15];
    const float* bl = (const float*)d_in[16];

    const int* src = ei;
    const int* dst = ei + N_EDGES;

    char* ws = (char*)d_ws;
    size_t off = 0;
    auto alloc = [&](size_t bytes) -> void* {
        void* p = ws + off;
        off += (bytes + 255) & ~(size_t)255;
        return p;
    };
    unsigned char*  hFa  = (unsigned char*)alloc((size_t)PADN * FDIM);        // fp8 ping
    unsigned char*  hFb  = (unsigned char*)alloc((size_t)PADN * FDIM);        // fp8 pong
    unsigned short* wp   = (unsigned short*)alloc((size_t)3 * 16384 * 2);
    float* dinv    = (float*)alloc((size_t)N_NODES * 4);
    int*   offs    = (int*)alloc((size_t)(N_NODES + 1) * 4);
    int*   csr_src = (int*)alloc((size_t)N_EDGES * 4);
    unsigned* binned = (unsigned*)alloc((size_t)NBUCK * CAPA * 4);
    int*   bcur    = (int*)alloc(256 * 4);
    float* pooled  = (float*)alloc((size_t)NUM_GRAPHS * FDIM * 4);

    hipMemsetAsync(bcur, 0, 256 * 4, stream);
    hipMemsetAsync(pooled, 0, (size_t)NUM_GRAPHS * FDIM * 4, stream);

    k_pre<<<BIN_BLOCKS + B_WPK, 256, 0, stream>>>(src, dst, bcur, binned,
                                                  W1, W2, W3, wp);
    k_binB<<<NBUCK, 256, 0, stream>>>(binned, bcur, offs, dinv, csr_src);

    int gemm_grid  = PADN / 128;          // 782
    int fuse_grid  = N_NODES / 32;        // 3125

    // layer 1 gemm (f32 x input, in-register bf16 conversion)
    k_gemm1<<<gemm_grid, 256, 0, stream>>>(x, wp, dinv, hFa);
    // fused: agg1+LN1+ReLU -> @W2
    k_fused<<<fuse_grid, 256, 0, stream>>>(hFa, wp + 16384, dinv, hFb,
                                           offs, csr_src, b1, g1, be1);
    // fused: agg2+LN2+ReLU -> @W3
    k_fused<<<fuse_grid, 256, 0, stream>>>(hFb, wp + 32768, dinv, hFa,
                                           offs, csr_src, b2, g2, be2);
    // agg3+LN3+ReLU + pooling
    k_aggpool<<<fuse_grid, 256, 0, stream>>>(hFa, offs, csr_src, dinv, batch,
                                             b3, g3, be3, pooled);
    // final projection
    k_final<<<NUM_GRAPHS, 64, 0, stream>>>(pooled, batch, Wl, bl, (float*)d_out);
}

// Round 18
// 235.807 us; speedup vs baseline: 2.3373x; 2.3373x over previous
//
#include <hip/hip_runtime.h>
#include <hip/hip_bf16.h>
#include <math.h>

#define N_NODES    100000
#define N_EDGES    1600000
#define FDIM       128
#define NUM_GRAPHS 512
#define EPS        1e-5f
#define PADN       100096           // 782 * 128

#define B_WPK   192                 // 3 * 64

#define NBUCK   196                 // ceil(100000/512)
#define CAPA    9216                // per-bucket capacity (mean 8163, sigma ~90)
#define EB_CHUNK 2048               // edges per binning block (proven optimum)
#define BIN_BLOCKS ((N_EDGES + EB_CHUNK - 1) / EB_CHUNK)   // 782
#define SEGSH   14                  // src segment = src >> 14
#define SEGN    8

typedef __attribute__((ext_vector_type(8))) __bf16 bf16x8;
typedef __attribute__((ext_vector_type(4))) float  f32x4;

__device__ __forceinline__ unsigned short f2bf(float f) {
    unsigned u = __builtin_bit_cast(unsigned, f);
    u += 0x7FFF + ((u >> 16) & 1);           // round-to-nearest-even
    return (unsigned short)(u >> 16);
}

// decode 4 packed fp8(e4m3) -> 4 floats
__device__ __forceinline__ void dec4(unsigned dw, float* o) {
    auto lo = __builtin_amdgcn_cvt_pk_f32_fp8(dw, false);
    auto hi = __builtin_amdgcn_cvt_pk_f32_fp8(dw, true);
    o[0] = lo[0]; o[1] = lo[1]; o[2] = hi[0]; o[3] = hi[1];
}

__device__ __forceinline__ void acc16(uint4 v, float* a) {
    float d[16];
    dec4(v.x, &d[0]); dec4(v.y, &d[4]); dec4(v.z, &d[8]); dec4(v.w, &d[12]);
#pragma unroll
    for (int f = 0; f < 16; f++) a[f] += d[f];
}

// agg core (float out): gather-sum dinv-pre-scaled fp8 rows for node i,
// di-scale + bias + LN + ReLU -> r[16] floats (features sl*16..sl*16+15)
// 4-deep gather ILP with cross-batch index prefetch (proven optimum, ~52 VGPR)
__device__ __forceinline__ void agg_core_f(const unsigned char* __restrict__ h8,
                                           const int* __restrict__ offs,
                                           const int* __restrict__ csr_src,
                                           float di, int i, int sl,
                                           const float* __restrict__ bias,
                                           const float* __restrict__ gamma,
                                           const float* __restrict__ beta,
                                           float* r) {
    size_t lofs16 = (size_t)sl * 16;
    float a[16];
    {
        uint4 v = *(const uint4*)(h8 + (size_t)i * 128 + lofs16);
        float d[16];
        dec4(v.x, &d[0]); dec4(v.y, &d[4]); dec4(v.z, &d[8]); dec4(v.w, &d[12]);
#pragma unroll
        for (int f = 0; f < 16; f++) a[f] = d[f];
    }

    int eBeg = offs[i], eEnd = offs[i + 1];
    int e = eBeg;
    int s0, s1, s2, s3;
    if (e + 4 <= eEnd) {
        s0 = csr_src[e + 0]; s1 = csr_src[e + 1];
        s2 = csr_src[e + 2]; s3 = csr_src[e + 3];
    }
    for (; e + 8 <= eEnd; e += 4) {
        uint4 v0 = *(const uint4*)(h8 + (size_t)s0 * 128 + lofs16);
        uint4 v1 = *(const uint4*)(h8 + (size_t)s1 * 128 + lofs16);
        uint4 v2 = *(const uint4*)(h8 + (size_t)s2 * 128 + lofs16);
        uint4 v3 = *(const uint4*)(h8 + (size_t)s3 * 128 + lofs16);
        s0 = csr_src[e + 4]; s1 = csr_src[e + 5];
        s2 = csr_src[e + 6]; s3 = csr_src[e + 7];
        acc16(v0, a); acc16(v1, a); acc16(v2, a); acc16(v3, a);
    }
    if (e + 4 <= eEnd) {
        uint4 v0 = *(const uint4*)(h8 + (size_t)s0 * 128 + lofs16);
        uint4 v1 = *(const uint4*)(h8 + (size_t)s1 * 128 + lofs16);
        uint4 v2 = *(const uint4*)(h8 + (size_t)s2 * 128 + lofs16);
        uint4 v3 = *(const uint4*)(h8 + (size_t)s3 * 128 + lofs16);
        acc16(v0, a); acc16(v1, a); acc16(v2, a); acc16(v3, a);
        e += 4;
    }
    for (; e < eEnd; ++e) {
        int s = csr_src[e];
        uint4 v = *(const uint4*)(h8 + (size_t)s * 128 + lofs16);
        acc16(v, a);
    }

    float4 b0 = *(const float4*)(bias + sl * 16);
    float4 b1 = *(const float4*)(bias + sl * 16 + 4);
    float4 b2 = *(const float4*)(bias + sl * 16 + 8);
    float4 b3 = *(const float4*)(bias + sl * 16 + 12);
    a[0]  = fmaf(a[0],  di, b0.x); a[1]  = fmaf(a[1],  di, b0.y);
    a[2]  = fmaf(a[2],  di, b0.z); a[3]  = fmaf(a[3],  di, b0.w);
    a[4]  = fmaf(a[4],  di, b1.x); a[5]  = fmaf(a[5],  di, b1.y);
    a[6]  = fmaf(a[6],  di, b1.z); a[7]  = fmaf(a[7],  di, b1.w);
    a[8]  = fmaf(a[8],  di, b2.x); a[9]  = fmaf(a[9],  di, b2.y);
    a[10] = fmaf(a[10], di, b2.z); a[11] = fmaf(a[11], di, b2.w);
    a[12] = fmaf(a[12], di, b3.x); a[13] = fmaf(a[13], di, b3.y);
    a[14] = fmaf(a[14], di, b3.z); a[15] = fmaf(a[15], di, b3.w);

    float s1v = 0.f, s2v = 0.f;
#pragma unroll
    for (int f = 0; f < 16; f++) { s1v += a[f]; s2v += a[f] * a[f]; }
#pragma unroll
    for (int off = 1; off < 8; off <<= 1) {
        s1v += __shfl_xor(s1v, off);
        s2v += __shfl_xor(s2v, off);
    }
    float mu   = s1v * (1.0f / 128.0f);
    float var  = s2v * (1.0f / 128.0f) - mu * mu;
    float rstd = rsqrtf(var + EPS);

    float4 g0 = *(const float4*)(gamma + sl * 16);
    float4 g1 = *(const float4*)(gamma + sl * 16 + 4);
    float4 g2 = *(const float4*)(gamma + sl * 16 + 8);
    float4 g3 = *(const float4*)(gamma + sl * 16 + 12);
    float4 e0v = *(const float4*)(beta + sl * 16);
    float4 e1v = *(const float4*)(beta + sl * 16 + 4);
    float4 e2v = *(const float4*)(beta + sl * 16 + 8);
    float4 e3v = *(const float4*)(beta + sl * 16 + 12);
    float g[16]  = {g0.x,g0.y,g0.z,g0.w, g1.x,g1.y,g1.z,g1.w,
                    g2.x,g2.y,g2.z,g2.w, g3.x,g3.y,g3.z,g3.w};
    float be[16] = {e0v.x,e0v.y,e0v.z,e0v.w, e1v.x,e1v.y,e1v.z,e1v.w,
                    e2v.x,e2v.y,e2v.z,e2v.w, e3v.x,e3v.y,e3v.z,e3v.w};

#pragma unroll
    for (int f = 0; f < 16; f++)
        r[f] = fmaxf((a[f] - mu) * rstd * g[f] + be[f], 0.f);
}

// ---------------- k_pre: edge binning ∥ W pack ------------------------------

__global__ __launch_bounds__(256) void k_pre(const int* __restrict__ src,
                                             const int* __restrict__ dst,
                                             int* __restrict__ bcur,
                                             unsigned* __restrict__ binned,
                                             const float* __restrict__ W1,
                                             const float* __restrict__ W2,
                                             const float* __restrict__ W3,
                                             unsigned short* __restrict__ wp) {
    __shared__ int hist[NBUCK];
    __shared__ int lbase[NBUCK];
    __shared__ int loff[NBUCK];
    __shared__ unsigned lpack[EB_CHUNK];
    __shared__ unsigned short lbuck[EB_CHUNK];
    int b = blockIdx.x;
    int t = threadIdx.x;
    if (b < BIN_BLOCKS) {
        int e0 = b * EB_CHUNK;
        int nE = min(EB_CHUNK, N_EDGES - e0);

        for (int j = t; j < NBUCK; j += 256) { hist[j] = 0; loff[j] = 0; }
        __syncthreads();

        for (int k = t; k < nE; k += 256) {
            int e  = e0 + k;
            int d  = dst[e];
            int bk = d >> 9;
            lpack[k] = (unsigned)src[e] | ((unsigned)(d & 511) << 17);
            lbuck[k] = (unsigned short)bk;
            atomicAdd(&hist[bk], 1);
        }
        __syncthreads();
        for (int j = t; j < NBUCK; j += 256)
            lbase[j] = atomicAdd(&bcur[j], hist[j]);
        __syncthreads();

        for (int k = t; k < nE; k += 256) {
            int bk = lbuck[k];
            int p  = lbase[bk] + atomicAdd(&loff[bk], 1);
            binned[(size_t)bk * CAPA + p] = lpack[k];
        }
    } else {
        int wb  = b - BIN_BLOCKS;
        int mat = wb >> 6;
        const float* W = (mat == 0) ? W1 : (mat == 1) ? W2 : W3;
        unsigned short* o = wp + (size_t)mat * 16384;
        int idx = (wb & 63) * 256 + t;
        int j  = idx & 7;
        int l  = (idx >> 3) & 63;
        int ct = (idx >> 9) & 7;
        int ks = idx >> 12;
        int k  = ks * 32 + (l >> 4) * 8 + j;
        int c  = ct * 16 + (l & 15);
        o[idx] = f2bf(W[k * 128 + c]);
    }
}

// ---------------- k_binB: 2-level counting sort (direct scatter) ------------

__global__ __launch_bounds__(256) void k_binB(const unsigned* __restrict__ binned,
                                              const int* __restrict__ bcur,
                                              int* __restrict__ offs,
                                              float* __restrict__ dinv,
                                              int* __restrict__ csr_src) {
    __shared__ int smem[512 * SEGN + 256];   // 17 KB
    int* cnt2 = smem;
    int* part = smem + 4096;
    int b = blockIdx.x;
    int t = threadIdx.x;
    int nb0 = b * 512;
    int cnt = bcur[b];

    int pv = (t < b) ? bcur[t] : 0;
#pragma unroll
    for (int off = 32; off; off >>= 1) pv += __shfl_down(pv, off);
    if ((t & 63) == 0) part[t >> 6] = pv;
    __syncthreads();
    int seg0 = part[0] + part[1] + part[2] + part[3];
    __syncthreads();

    for (int j = t; j < 512 * SEGN; j += 256) cnt2[j] = 0;
    __syncthreads();

    for (int k = t; k < cnt; k += 256) {
        unsigned v = binned[(size_t)b * CAPA + k];
        atomicAdd(&cnt2[(v >> 17) * SEGN + ((v & 0x1FFFF) >> SEGSH)], 1);
    }
    __syncthreads();

    int base16 = t * 16;
    int lsum[16];
    int run = 0;
#pragma unroll
    for (int q = 0; q < 16; q++) { lsum[q] = run; run += cnt2[base16 + q]; }
    int deg0 = lsum[8];
    int deg1 = run - lsum[8];
    part[t] = run;
    __syncthreads();
    for (int off = 1; off < 256; off <<= 1) {
        int y = 0;
        if (t >= off) y = part[t - off];
        __syncthreads();
        if (t >= off) part[t] += y;
        __syncthreads();
    }
    int excl = part[t] - run;
#pragma unroll
    for (int q = 0; q < 16; q++) cnt2[base16 + q] = excl + lsum[q];

    {
        int n0 = nb0 + 2 * t;
        if (n0 < N_NODES) {
            offs[n0] = seg0 + excl;
            dinv[n0] = rsqrtf(1.0f + (float)deg0);
        }
        if (n0 + 1 < N_NODES) {
            offs[n0 + 1] = seg0 + excl + lsum[8];
            dinv[n0 + 1] = rsqrtf(1.0f + (float)deg1);
        }
    }
    if (b == NBUCK - 1 && t == 0) offs[N_NODES] = N_EDGES;
    __syncthreads();

    for (int k = t; k < cnt; k += 256) {
        unsigned v = binned[(size_t)b * CAPA + k];
        int p = atomicAdd(&cnt2[(v >> 17) * SEGN + ((v & 0x1FFFF) >> SEGSH)], 1);
        csr_src[seg0 + p] = (int)(v & 0x1FFFF);
    }
}

// ---------------- k_gemm1: C8 = fp8( dinv * (f32 x @ W1) ) ------------------

__global__ __launch_bounds__(256) void k_gemm1(const float* __restrict__ X,
                                               const unsigned short* __restrict__ Wp,
                                               const float* __restrict__ dinv,
                                               unsigned char* __restrict__ C8) {
    int t    = threadIdx.x;
    int lane = t & 63;
    int w    = t >> 6;
    int wc   = w & 1;
    int wr   = w >> 1;
    int rb   = blockIdx.x * 128 + wr * 64 + (lane & 15);
    int koff = (lane >> 4) * 8;

    f32x4 acc[4][4];
#pragma unroll
    for (int c = 0; c < 4; c++)
#pragma unroll
        for (int r = 0; r < 4; r++) acc[c][r] = (f32x4){0.f, 0.f, 0.f, 0.f};

    const bf16x8* Wv = (const bf16x8*)Wp;
#pragma unroll
    for (int ks = 0; ks < 4; ++ks) {
        bf16x8 fw[4], fa[4];
#pragma unroll
        for (int c = 0; c < 4; ++c)
            fw[c] = Wv[(ks * 8 + wc * 4 + c) * 64 + lane];
#pragma unroll
        for (int r = 0; r < 4; ++r) {
            int row = rb + r * 16;
            ushort4 lo = {0,0,0,0}, hi = {0,0,0,0};
            if (row < N_NODES) {
                const float* xp = X + (size_t)row * 128 + ks * 32 + koff;
                float4 xv0 = *(const float4*)xp;
                float4 xv1 = *(const float4*)(xp + 4);
                lo.x = f2bf(xv0.x); lo.y = f2bf(xv0.y);
                lo.z = f2bf(xv0.z); lo.w = f2bf(xv0.w);
                hi.x = f2bf(xv1.x); hi.y = f2bf(xv1.y);
                hi.z = f2bf(xv1.z); hi.w = f2bf(xv1.w);
            }
            uint4 packed = make_uint4(
                (unsigned)lo.x | ((unsigned)lo.y << 16),
                (unsigned)lo.z | ((unsigned)lo.w << 16),
                (unsigned)hi.x | ((unsigned)hi.y << 16),
                (unsigned)hi.z | ((unsigned)hi.w << 16));
            fa[r] = __builtin_bit_cast(bf16x8, packed);
        }
#pragma unroll
        for (int c = 0; c < 4; ++c)
#pragma unroll
            for (int r = 0; r < 4; ++r)
                acc[c][r] = __builtin_amdgcn_mfma_f32_16x16x32_bf16(fw[c], fa[r], acc[c][r], 0, 0, 0);
    }

#pragma unroll
    for (int r = 0; r < 4; ++r) {
        int row = blockIdx.x * 128 + wr * 64 + r * 16 + (lane & 15);
        if (row < N_NODES) {
            float dv = dinv[row];
#pragma unroll
            for (int c = 0; c < 4; ++c) {
                int col = (wc * 4 + c) * 16 + (lane >> 4) * 4;
                unsigned u = __builtin_amdgcn_cvt_pk_fp8_f32(acc[c][r][0] * dv, acc[c][r][1] * dv, 0, false);
                u = (unsigned)__builtin_amdgcn_cvt_pk_fp8_f32(acc[c][r][2] * dv, acc[c][r][3] * dv, (int)u, true);
                *(unsigned*)(C8 + (size_t)row * 128 + col) = u;
            }
        }
    }
}

// ---------------- k_fused: agg(l)+LN+ReLU -> 32-row LDS tile -> @W(l+1) -----

__global__ __launch_bounds__(256, 4) void k_fused(const unsigned char* __restrict__ h8_in,
                                                  const unsigned short* __restrict__ Wp,
                                                  const float* __restrict__ dinv,
                                                  unsigned char* __restrict__ h8_out,
                                                  const int* __restrict__ offs,
                                                  const int* __restrict__ csr_src,
                                                  const float* __restrict__ bias,
                                                  const float* __restrict__ gamma,
                                                  const float* __restrict__ beta) {
    __shared__ unsigned tile_u[32 * 64];      // 8 KB
    int t    = threadIdx.x;
    int lane = t & 63;
    int w    = t >> 6;
    int grp  = lane >> 3;
    int sl   = lane & 7;
    int nt   = w * 8 + grp;                   // 0..31
    int i    = blockIdx.x * 32 + nt;          // 3125*32 == 100000

    {
        float r[16];
        agg_core_f(h8_in, offs, csr_src, dinv[i], i, sl, bias, gamma, beta, r);
        unsigned ow[8];
#pragma unroll
        for (int f = 0; f < 8; f++)
            ow[f] = (unsigned)f2bf(r[2 * f]) | ((unsigned)f2bf(r[2 * f + 1]) << 16);
        int rowbase = nt * 64;
        int colu    = sl * 8;
        int swz0 = (colu    ) ^ ((nt & 15) << 2);
        int swz1 = (colu + 4) ^ ((nt & 15) << 2);
        *(uint4*)&tile_u[rowbase + swz0] = make_uint4(ow[0], ow[1], ow[2], ow[3]);
        *(uint4*)&tile_u[rowbase + swz1] = make_uint4(ow[4], ow[5], ow[6], ow[7]);
    }
    __syncthreads();

    f32x4 acc[2][2];
#pragma unroll
    for (int c = 0; c < 2; c++)
#pragma unroll
        for (int r = 0; r < 2; r++) acc[c][r] = (f32x4){0.f, 0.f, 0.f, 0.f};

    const bf16x8* Wv = (const bf16x8*)Wp;
#pragma unroll
    for (int ks = 0; ks < 4; ++ks) {
        bf16x8 fw[2], fa[2];
#pragma unroll
        for (int c = 0; c < 2; ++c)
            fw[c] = Wv[(ks * 8 + w * 2 + c) * 64 + lane];
#pragma unroll
        for (int r = 0; r < 2; ++r) {
            int lr   = r * 16 + (lane & 15);
            int colu = ks * 16 + (lane >> 4) * 4;
            int swz  = colu ^ ((lr & 15) << 2);
            uint4 v = *(const uint4*)&tile_u[lr * 64 + swz];
            fa[r] = __builtin_bit_cast(bf16x8, v);
        }
#pragma unroll
        for (int c = 0; c < 2; ++c)
#pragma unroll
            for (int r = 0; r < 2; ++r)
                acc[c][r] = __builtin_amdgcn_mfma_f32_16x16x32_bf16(fw[c], fa[r], acc[c][r], 0, 0, 0);
    }

#pragma unroll
    for (int r = 0; r < 2; ++r) {
        int row = blockIdx.x * 32 + r * 16 + (lane & 15);
        float dv = dinv[row];
#pragma unroll
        for (int c = 0; c < 2; ++c) {
            int col = (w * 2 + c) * 16 + (lane >> 4) * 4;
            unsigned u = __builtin_amdgcn_cvt_pk_fp8_f32(acc[c][r][0] * dv, acc[c][r][1] * dv, 0, false);
            u = (unsigned)__builtin_amdgcn_cvt_pk_fp8_f32(acc[c][r][2] * dv, acc[c][r][3] * dv, (int)u, true);
            *(unsigned*)(h8_out + (size_t)row * 128 + col) = u;
        }
    }
}

// ---------------- k_aggpool: agg3+LN3+ReLU + per-graph pooled sums ----------

__global__ __launch_bounds__(256) void k_aggpool(const unsigned char* __restrict__ h8,
                                                 const int* __restrict__ offs,
                                                 const int* __restrict__ csr_src,
                                                 const float* __restrict__ dinv,
                                                 const int* __restrict__ batch,
                                                 const float* __restrict__ bias,
                                                 const float* __restrict__ gamma,
                                                 const float* __restrict__ beta,
                                                 float* __restrict__ pooled) {
    __shared__ float wsum[4][128];
    __shared__ int grange[2];
    int t    = threadIdx.x;
    int lane = t & 63;
    int w    = t >> 6;
    int grp  = lane >> 3;
    int sl   = lane & 7;
    int i    = blockIdx.x * 32 + w * 8 + grp;   // 3125*32 == 100000

    float r[16];
    agg_core_f(h8, offs, csr_src, dinv[i], i, sl, bias, gamma, beta, r);

    int bg = batch[i];
    if (t == 0) {
        grange[0] = batch[blockIdx.x * 32];
        grange[1] = batch[blockIdx.x * 32 + 31];
    }
    __syncthreads();
    int g0 = grange[0], g1 = grange[1];

    for (int g = g0; g <= g1; ++g) {
        float v[16];
        bool in = (bg == g);
#pragma unroll
        for (int f = 0; f < 16; f++) v[f] = in ? r[f] : 0.f;
#pragma unroll
        for (int f = 0; f < 16; f++) {
            v[f] += __shfl_xor(v[f], 8);
            v[f] += __shfl_xor(v[f], 16);
            v[f] += __shfl_xor(v[f], 32);
        }
        if (grp == 0) {
#pragma unroll
            for (int f = 0; f < 16; f++) wsum[w][sl * 16 + f] = v[f];
        }
        __syncthreads();
        if (t < 128) {
            float s = wsum[0][t] + wsum[1][t] + wsum[2][t] + wsum[3][t];
            if (s != 0.f) atomicAdd(&pooled[(size_t)g * 128 + t], s);
        }
        __syncthreads();
    }
}

// ---------------- k_final: out[g] = (pooled[g]/cnt[g]) . Wl + bl ------------

__global__ __launch_bounds__(64) void k_final(const float* __restrict__ pooled,
                                              const int* __restrict__ batch,
                                              const float* __restrict__ Wl,
                                              const float* __restrict__ bl,
                                              float* __restrict__ out) {
    int g = blockIdx.x;
    int lane = threadIdx.x;

    int lo = 0, hi = N_NODES;
    while (lo < hi) { int mid = (lo + hi) >> 1; if (batch[mid] < g) lo = mid + 1; else hi = mid; }
    int s = lo;
    lo = s; hi = N_NODES;
    while (lo < hi) { int mid = (lo + hi) >> 1; if (batch[mid] < g + 1) lo = mid + 1; else hi = mid; }
    int e = lo;

    float inv = 1.0f / fmaxf((float)(e - s), 1.0f);
    float2 p2 = ((const float2*)(pooled + (size_t)g * 128))[lane];
    float p = p2.x * inv * Wl[lane * 2] + p2.y * inv * Wl[lane * 2 + 1];
#pragma unroll
    for (int off = 32; off; off >>= 1) p += __shfl_xor(p, off);
    if (lane == 0) out[g] = p + bl[0];
}

// ---------------- launch ----------------

extern "C" void kernel_launch(void* const* d_in, const int* in_sizes, int n_in,
                              void* d_out, int out_size, void* d_ws, size_t ws_size,
                              hipStream_t stream) {
    const float* x     = (const float*)d_in[0];
    const int*   ei    = (const int*)d_in[1];
    const int*   batch = (const int*)d_in[2];
    const float* W1 = (const float*)d_in[3];
    const float* b1 = (const float*)d_in[4];
    const float* g1 = (const float*)d_in[5];
    const float* be1 = (const float*)d_in[6];
    const float* W2 = (const float*)d_in[7];
    const float* b2 = (const float*)d_in[8];
    const float* g2 = (const float*)d_in[9];
    const float* be2 = (const float*)d_in[10];
    const float* W3 = (const float*)d_in[11];
    const float* b3 = (const float*)d_in[12];
    const float* g3 = (const float*)d_in[13];
    const float* be3 = (const float*)d_in[14];
    const float* Wl = (const float*)d_in[15];
    const float* bl = (const float*)d_in[16];

    const int* src = ei;
    const int* dst = ei + N_EDGES;

    char* ws = (char*)d_ws;
    size_t off = 0;
    auto alloc = [&](size_t bytes) -> void* {
        void* p = ws + off;
        off += (bytes + 255) & ~(size_t)255;
        return p;
    };
    unsigned char*  hFa  = (unsigned char*)alloc((size_t)PADN * FDIM);        // fp8 ping
    unsigned char*  hFb  = (unsigned char*)alloc((size_t)PADN * FDIM);        // fp8 pong
    unsigned short* wp   = (unsigned short*)alloc((size_t)3 * 16384 * 2);
    float* dinv    = (float*)alloc((size_t)N_NODES * 4);
    int*   offs    = (int*)alloc((size_t)(N_NODES + 1) * 4);
    int*   csr_src = (int*)alloc((size_t)N_EDGES * 4);
    unsigned* binned = (unsigned*)alloc((size_t)NBUCK * CAPA * 4);
    int*   bcur    = (int*)alloc(256 * 4);
    float* pooled  = (float*)alloc((size_t)NUM_GRAPHS * FDIM * 4);

    hipMemsetAsync(bcur, 0, 256 * 4, stream);
    hipMemsetAsync(pooled, 0, (size_t)NUM_GRAPHS * FDIM * 4, stream);

    k_pre<<<BIN_BLOCKS + B_WPK, 256, 0, stream>>>(src, dst, bcur, binned,
                                                  W1, W2, W3, wp);
    k_binB<<<NBUCK, 256, 0, stream>>>(binned, bcur, offs, dinv, csr_src);

    int gemm_grid  = PADN / 128;          // 782
    int fuse_grid  = N_NODES / 32;        // 3125

    // layer 1 gemm (f32 x input, in-register bf16 conversion)
    k_gemm1<<<gemm_grid, 256, 0, stream>>>(x, wp, dinv, hFa);
    // fused: agg1+LN1+ReLU -> @W2
    k_fused<<<fuse_grid, 256, 0, stream>>>(hFa, wp + 16384, dinv, hFb,
                                           offs, csr_src, b1, g1, be1);
    // fused: agg2+LN2+ReLU -> @W3
    k_fused<<<fuse_grid, 256, 0, stream>>>(hFb, wp + 32768, dinv, hFa,
                                           offs, csr_src, b2, g2, be2);
    // agg3+LN3+ReLU + pooling
    k_aggpool<<<fuse_grid, 256, 0, stream>>>(hFa, offs, csr_src, dinv, batch,
                                             b3, g3, be3, pooled);
    // final projection
    k_final<<<NUM_GRAPHS, 64, 0, stream>>>(pooled, batch, Wl, bl, (float*)d_out);
}